// Round 7
// baseline (46.286 us; speedup 1.0000x reference)
//
#include <hip/hip_runtime.h>
#include <math.h>

constexpr int N   = 8192;
constexpr int K   = 30;
constexpr int TPB = 256;
constexpr int NI  = 32;                 // i-chunks of 256
constexpr int NJ  = 32;                 // j-chunks of 256
constexpr int NBLK = NI * NJ;           // 1024 blocks -> 4 blocks/CU

// d_ws layout:
//   [0, 4)            int     ticket      (re-zeroed each launch via memsetAsync)
//   [16, 16+8192)     double  pnum[1024]
//   [8208, 8208+4096) int     pcnt[1024]

__device__ __forceinline__ double mrl_row(const float* __restrict__ est,
                                          const float* __restrict__ intervals,
                                          int row) {
    // f32 hardware exp + f64 accumulation (proven numerics from R4/R5)
    const float2* e2 = (const float2*)(est + row * K);   // rows are 8B-aligned (120B stride)
    double sp = 1.0, m = 0.0;
#pragma unroll
    for (int k2 = 0; k2 < K / 2; ++k2) {
        float2 ev = e2[k2];
        float h0f = 1.0f / (1.0f + __expf(-ev.x));
        float h1f = 1.0f / (1.0f + __expf(-ev.y));
        double h0 = (double)h0f, h1 = (double)h1f;
        m += (double)intervals[2 * k2] * h0 * sp;
        sp *= (1.0 - h0);
        m += (double)intervals[2 * k2 + 1] * h1 * sp;
        sp *= (1.0 - h1);
    }
    return m;
}

__global__ void fused_kernel(const float* __restrict__ est,
                             const float* __restrict__ target,
                             const float* __restrict__ intervals,
                             int* __restrict__ ticket,
                             double* __restrict__ pnum,
                             int* __restrict__ pcnt,
                             float* __restrict__ out) {
    __shared__ float  s_t[TPB];
    __shared__ float  s_m[TPB];
    __shared__ double r_num[TPB];
    __shared__ int    r_cnt[TPB];
    __shared__ int    s_flag;

    const int tid = threadIdx.x;
    const int bid = blockIdx.x;
    const int ib  = bid >> 5;           // i-chunk
    const int js  = bid & 31;           // j-chunk
    const int i   = ib * TPB + tid;
    const int j   = js * TPB + tid;

    const float2 ti2 = ((const float2*)target)[i];
    const float  ti  = ti2.x;
    const bool   ei  = (ti2.y != 0.0f);

    // inline mrl for own i-row and this block's j-row (est is L2-resident)
    const double mi_d = mrl_row(est, intervals, i);
    float mj;
    if (ib == js) {                      // block-uniform branch
        mj = (float)mi_d;
    } else {
        mj = (float)mrl_row(est, intervals, j);
    }
    const float mi = (float)mi_d;

    s_t[tid] = ((const float2*)target)[j].x;
    s_m[tid] = mj;
    __syncthreads();

    const float4* s_t4 = (const float4*)s_t;
    const float4* s_m4 = (const float4*)s_m;

    double smj = 0.0;                    // f64 chunk accumulator
    int c0 = 0, c1 = 0, c2 = 0, c3 = 0;

#pragma unroll
    for (int ch = 0; ch < TPB / 64; ++ch) {          // 4 chunks of 64 pairs
        float a0 = 0.f, a1 = 0.f, a2 = 0.f, a3 = 0.f;
#pragma unroll
        for (int q = 0; q < 16; ++q) {               // 16 x 4 pairs
            const int jj4 = ch * 16 + q;
            // broadcast ds_read_b128 (uniform address) -> conflict-free
            float4 tv = s_t4[jj4];
            float4 mv = s_m4[jj4];
            bool b0 = ti < tv.x, b1 = ti < tv.y, b2 = ti < tv.z, b3 = ti < tv.w;
            c0 += b0; a0 += b0 ? mv.x : 0.0f;
            c1 += b1; a1 += b1 ? mv.y : 0.0f;
            c2 += b2; a2 += b2 ? mv.z : 0.0f;
            c3 += b3; a3 += b3 ? mv.w : 0.0f;
        }
        smj += (double)((a0 + a1) + (a2 + a3));      // flush every 64 pairs
    }

    const int cnt = (c0 + c1) + (c2 + c3);
    r_num[tid] = ei ? ((double)cnt * (double)mi - smj) : 0.0;
    r_cnt[tid] = ei ? cnt : 0;
    __syncthreads();
    for (int s = TPB / 2; s > 0; s >>= 1) {
        if (tid < s) {
            r_num[tid] += r_num[tid + s];
            r_cnt[tid] += r_cnt[tid + s];
        }
        __syncthreads();
    }

    if (tid == 0) {
        pnum[bid] = r_num[0];
        pcnt[bid] = r_cnt[0];
        // publish partials, then take a ticket (agent/device scope)
        __threadfence();
        int old = atomicAdd(ticket, 1);   // device-scope by default on gfx950
        s_flag = (old == NBLK - 1);
    }
    __syncthreads();

    if (s_flag) {                        // exactly one block; block-uniform
        // acquire side: fence before reading other blocks' partials
        __threadfence();
        double n = 0.0;
        int    c = 0;
#pragma unroll
        for (int p = 0; p < NBLK / TPB; ++p) {       // fixed order -> deterministic
            n += pnum[p * TPB + tid];
            c += pcnt[p * TPB + tid];
        }
        r_num[tid] = n;
        r_cnt[tid] = c;
        __syncthreads();
        for (int s = TPB / 2; s > 0; s >>= 1) {
            if (tid < s) {
                r_num[tid] += r_num[tid + s];
                r_cnt[tid] += r_cnt[tid + s];
            }
            __syncthreads();
        }
        if (tid == 0) out[0] = (float)(r_num[0] / (double)r_cnt[0]);
    }
}

extern "C" void kernel_launch(void* const* d_in, const int* in_sizes, int n_in,
                              void* d_out, int out_size, void* d_ws, size_t ws_size,
                              hipStream_t stream) {
    const float* est       = (const float*)d_in[0];   // (N, K) fp32
    const float* target    = (const float*)d_in[1];   // (N, 2) fp32
    const float* intervals = (const float*)d_in[2];   // (K,)  fp32
    float* out = (float*)d_out;

    int*    ticket = (int*)d_ws;
    double* pnum   = (double*)((char*)d_ws + 16);
    int*    pcnt   = (int*)((char*)d_ws + 16 + 8192);

    (void)hipMemsetAsync(d_ws, 0, 4, stream);   // reset ticket (ws poisoned once)
    fused_kernel<<<NBLK, TPB, 0, stream>>>(est, target, intervals,
                                           ticket, pnum, pcnt, out);
}

// Round 8
// 40.736 us; speedup vs baseline: 1.1362x; 1.1362x over previous
//
#include <hip/hip_runtime.h>
#include <math.h>

constexpr int N   = 8192;
constexpr int K   = 30;
constexpr int TPB = 256;
constexpr int NI  = 32;                 // i-chunks of 256
constexpr int NJ  = 32;                 // j-chunks of 256
constexpr int NBLK = NI * NJ;           // 1024 blocks -> 4 blocks/CU

// d_ws layout:
//   [0, 4)                 int     ticket   (re-zeroed each launch via memsetAsync)
//   [16, 16+32768)         float   mrl[N]
//   [32784, 32784+8192)    double  pnum[NBLK]   (32784 % 8 == 0)
//   [40976, 40976+4096)    int     pcnt[NBLK]
// total 45072 B  (ws >= 69632 B proven in R1)

__global__ void mrl_kernel(const float* __restrict__ est,
                           const float* __restrict__ intervals,
                           float* __restrict__ mrl) {
    __shared__ float s_est[TPB * K];     // 30720 B, this block's 256 rows

    const int tid = threadIdx.x;
    const int row0 = blockIdx.x * TPB;

    // coalesced staging: 256x30 floats = 3840 float2, 15 per thread
    const float2* src = (const float2*)(est + (size_t)row0 * K);
    float2* dst = (float2*)s_est;
#pragma unroll
    for (int t = 0; t < (TPB * K) / (2 * TPB); ++t)   // 15
        dst[t * TPB + tid] = src[t * TPB + tid];
    __syncthreads();

    const float* e = s_est + tid * K;
    double sp = 1.0, m = 0.0;            // f64 accumulation (proven R4/R5)
#pragma unroll
    for (int k = 0; k < K; ++k) {
        float hf = 1.0f / (1.0f + __expf(-e[k]));   // hardware v_exp_f32
        double h = (double)hf;
        m += (double)intervals[k] * h * sp;
        sp *= (1.0 - h);
    }
    mrl[row0 + tid] = (float)m;
}

__global__ void pair_final_kernel(const float* __restrict__ target,
                                  const float* __restrict__ mrl,
                                  int* __restrict__ ticket,
                                  double* __restrict__ pnum,
                                  int* __restrict__ pcnt,
                                  float* __restrict__ out) {
    __shared__ float  s_t[TPB];
    __shared__ float  s_m[TPB];
    __shared__ double r_num[TPB];
    __shared__ int    r_cnt[TPB];
    __shared__ int    s_flag;

    const int tid = threadIdx.x;
    const int bid = blockIdx.x;
    const int ib  = bid >> 5;           // i-chunk
    const int js  = bid & 31;           // j-chunk
    const int i   = ib * TPB + tid;
    const int j   = js * TPB + tid;

    const float2 ti2 = ((const float2*)target)[i];
    const float  ti  = ti2.x;
    const bool   ei  = (ti2.y != 0.0f);
    const float  mi  = mrl[i];

    // stage this block's j-chunk (coalesced)
    s_t[tid] = ((const float2*)target)[j].x;
    s_m[tid] = mrl[j];
    __syncthreads();

    const float4* s_t4 = (const float4*)s_t;
    const float4* s_m4 = (const float4*)s_m;

    double smj = 0.0;                    // f64 chunk accumulator
    int c0 = 0, c1 = 0, c2 = 0, c3 = 0;

#pragma unroll
    for (int ch = 0; ch < TPB / 64; ++ch) {          // 4 chunks of 64 pairs
        float a0 = 0.f, a1 = 0.f, a2 = 0.f, a3 = 0.f;
#pragma unroll
        for (int q = 0; q < 16; ++q) {               // 16 x 4 pairs
            const int jj4 = ch * 16 + q;
            // broadcast ds_read_b128 (uniform address) -> conflict-free
            float4 tv = s_t4[jj4];
            float4 mv = s_m4[jj4];
            bool b0 = ti < tv.x, b1 = ti < tv.y, b2 = ti < tv.z, b3 = ti < tv.w;
            c0 += b0; a0 += b0 ? mv.x : 0.0f;
            c1 += b1; a1 += b1 ? mv.y : 0.0f;
            c2 += b2; a2 += b2 ? mv.z : 0.0f;
            c3 += b3; a3 += b3 ? mv.w : 0.0f;
        }
        smj += (double)((a0 + a1) + (a2 + a3));      // flush every 64 pairs
    }

    const int cnt = (c0 + c1) + (c2 + c3);
    r_num[tid] = ei ? ((double)cnt * (double)mi - smj) : 0.0;
    r_cnt[tid] = ei ? cnt : 0;
    __syncthreads();
    for (int s = TPB / 2; s > 0; s >>= 1) {
        if (tid < s) {
            r_num[tid] += r_num[tid + s];
            r_cnt[tid] += r_cnt[tid + s];
        }
        __syncthreads();
    }

    if (tid == 0) {
        pnum[bid] = r_num[0];
        pcnt[bid] = r_cnt[0];
        __threadfence();                 // publish partials (agent scope)
        int old = atomicAdd(ticket, 1);  // device-scope by default on gfx950
        s_flag = (old == NBLK - 1);
    }
    __syncthreads();

    if (s_flag) {                        // exactly one block; block-uniform
        __threadfence();                 // acquire side before reading partials
        double n = 0.0;
        int    c = 0;
#pragma unroll
        for (int p = 0; p < NBLK / TPB; ++p) {       // fixed order -> deterministic
            n += pnum[p * TPB + tid];
            c += pcnt[p * TPB + tid];
        }
        r_num[tid] = n;
        r_cnt[tid] = c;
        __syncthreads();
        for (int s = TPB / 2; s > 0; s >>= 1) {
            if (tid < s) {
                r_num[tid] += r_num[tid + s];
                r_cnt[tid] += r_cnt[tid + s];
            }
            __syncthreads();
        }
        if (tid == 0) out[0] = (float)(r_num[0] / (double)r_cnt[0]);
    }
}

extern "C" void kernel_launch(void* const* d_in, const int* in_sizes, int n_in,
                              void* d_out, int out_size, void* d_ws, size_t ws_size,
                              hipStream_t stream) {
    const float* est       = (const float*)d_in[0];   // (N, K) fp32
    const float* target    = (const float*)d_in[1];   // (N, 2) fp32
    const float* intervals = (const float*)d_in[2];   // (K,)  fp32
    float* out = (float*)d_out;

    int*    ticket = (int*)d_ws;
    float*  mrl    = (float*)((char*)d_ws + 16);
    double* pnum   = (double*)((char*)d_ws + 32784);
    int*    pcnt   = (int*)((char*)d_ws + 40976);

    (void)hipMemsetAsync(d_ws, 0, 4, stream);   // reset ticket (ws poisoned once)
    mrl_kernel<<<NI, TPB, 0, stream>>>(est, intervals, mrl);
    pair_final_kernel<<<NBLK, TPB, 0, stream>>>(target, mrl, ticket,
                                                pnum, pcnt, out);
}

// Round 9
// 20.422 us; speedup vs baseline: 2.2664x; 1.9947x over previous
//
#include <hip/hip_runtime.h>
#include <math.h>

constexpr int N    = 8192;
constexpr int K    = 30;
constexpr int TPB  = 256;
constexpr int IPT  = 2;                   // i-rows per thread
constexpr int ISPAN = TPB * IPT;          // 512 i per block
constexpr int NI   = N / ISPAN;           // 16 i-chunks
constexpr int NJ   = 64;                  // j-slices
constexpr int JSPAN = N / NJ;             // 128 j per block
constexpr int NBLK = NI * NJ;             // 1024 blocks -> 8 blocks/CU

// d_ws layout:
//   [0, 32768)        float   mrl[N]
//   [32768, 40960)    double  pnum[NBLK]
//   [40960, 45056)    int     pcnt[NBLK]

__global__ void mrl_kernel(const float* __restrict__ est,
                           const float* __restrict__ intervals,
                           float* __restrict__ mrl) {
    __shared__ float s_est[TPB * K];      // this block's 256 rows, 30 KB

    const int tid  = threadIdx.x;
    const int row0 = blockIdx.x * TPB;

    // coalesced staging: 256x30 floats = 3840 float2, 15 per thread
    const float2* src = (const float2*)(est + (size_t)row0 * K);
    float2* dst = (float2*)s_est;
#pragma unroll
    for (int t = 0; t < (TPB * K) / (2 * TPB); ++t)   // 15
        dst[t * TPB + tid] = src[t * TPB + tid];
    __syncthreads();

    const float* e = s_est + tid * K;
    double sp = 1.0, m = 0.0;             // f64 accumulation (proven R4/R5)
#pragma unroll
    for (int k = 0; k < K; ++k) {
        float hf = 1.0f / (1.0f + __expf(-e[k]));   // hardware v_exp_f32
        double h = (double)hf;
        m += (double)intervals[k] * h * sp;
        sp *= (1.0 - h);
    }
    mrl[row0 + tid] = (float)m;
}

__global__ void pair_kernel(const float* __restrict__ target,
                            const float* __restrict__ mrl,
                            double* __restrict__ pnum,
                            int* __restrict__ pcnt) {
    __shared__ float  s_t[JSPAN];
    __shared__ float  s_m[JSPAN];
    __shared__ double r_num[TPB];
    __shared__ int    r_cnt[TPB];

    const int tid = threadIdx.x;
    const int bid = blockIdx.x;
    const int ib  = bid >> 6;             // i-chunk (of 512 rows)
    const int js  = bid & (NJ - 1);       // j-slice

    const int i0 = ib * ISPAN + tid;
    const int i1 = i0 + TPB;

    const float2 t0v = ((const float2*)target)[i0];
    const float2 t1v = ((const float2*)target)[i1];
    const float ti0 = t0v.x;  const bool e0 = (t0v.y != 0.0f);
    const float ti1 = t1v.x;  const bool e1 = (t1v.y != 0.0f);
    const float mi0 = mrl[i0];
    const float mi1 = mrl[i1];

    if (tid < JSPAN) {
        const int j = js * JSPAN + tid;
        s_t[tid] = ((const float2*)target)[j].x;
        s_m[tid] = mrl[j];
    }
    __syncthreads();

    const float4* s_t4 = (const float4*)s_t;
    const float4* s_m4 = (const float4*)s_m;

    double smj0 = 0.0, smj1 = 0.0;        // f64 chunk accumulators
    int c00 = 0, c01 = 0, c02 = 0, c03 = 0;
    int c10 = 0, c11 = 0, c12 = 0, c13 = 0;

#pragma unroll
    for (int ch = 0; ch < JSPAN / 64; ++ch) {        // 2 chunks of 64 j
        float a00 = 0.f, a01 = 0.f, a02 = 0.f, a03 = 0.f;
        float a10 = 0.f, a11 = 0.f, a12 = 0.f, a13 = 0.f;
#pragma unroll
        for (int q = 0; q < 16; ++q) {               // 16 x 4 j
            const int jj4 = ch * 16 + q;
            // broadcast ds_read_b128 (uniform address) -> conflict-free;
            // each read pair feeds 8 pair-updates (2 i-rows)
            float4 tv = s_t4[jj4];
            float4 mv = s_m4[jj4];
            {
                bool b0 = ti0 < tv.x, b1 = ti0 < tv.y, b2 = ti0 < tv.z, b3 = ti0 < tv.w;
                c00 += b0; a00 += b0 ? mv.x : 0.0f;
                c01 += b1; a01 += b1 ? mv.y : 0.0f;
                c02 += b2; a02 += b2 ? mv.z : 0.0f;
                c03 += b3; a03 += b3 ? mv.w : 0.0f;
            }
            {
                bool b0 = ti1 < tv.x, b1 = ti1 < tv.y, b2 = ti1 < tv.z, b3 = ti1 < tv.w;
                c10 += b0; a10 += b0 ? mv.x : 0.0f;
                c11 += b1; a11 += b1 ? mv.y : 0.0f;
                c12 += b2; a12 += b2 ? mv.z : 0.0f;
                c13 += b3; a13 += b3 ? mv.w : 0.0f;
            }
        }
        smj0 += (double)((a00 + a01) + (a02 + a03)); // flush every 64 pairs
        smj1 += (double)((a10 + a11) + (a12 + a13));
    }

    const int cnt0 = (c00 + c01) + (c02 + c03);
    const int cnt1 = (c10 + c11) + (c12 + c13);

    double num = 0.0;
    int    cnt = 0;
    if (e0) { num += (double)cnt0 * (double)mi0 - smj0; cnt += cnt0; }
    if (e1) { num += (double)cnt1 * (double)mi1 - smj1; cnt += cnt1; }

    r_num[tid] = num;
    r_cnt[tid] = cnt;
    __syncthreads();
    for (int s = TPB / 2; s > 0; s >>= 1) {
        if (tid < s) {
            r_num[tid] += r_num[tid + s];
            r_cnt[tid] += r_cnt[tid + s];
        }
        __syncthreads();
    }
    if (tid == 0) {
        pnum[bid] = r_num[0];
        pcnt[bid] = r_cnt[0];
    }
}

__global__ void final_kernel(const double* __restrict__ pnum,
                             const int* __restrict__ pcnt,
                             float* __restrict__ out) {
    __shared__ double r_num[TPB];
    __shared__ int    r_cnt[TPB];
    const int tid = threadIdx.x;
    double n = 0.0;
    int    c = 0;
#pragma unroll
    for (int p = 0; p < NBLK / TPB; ++p) {           // 4, fixed order
        const int idx = p * TPB + tid;
        n += pnum[idx];
        c += pcnt[idx];
    }
    r_num[tid] = n;
    r_cnt[tid] = c;
    __syncthreads();
    for (int s = TPB / 2; s > 0; s >>= 1) {
        if (tid < s) {
            r_num[tid] += r_num[tid + s];
            r_cnt[tid] += r_cnt[tid + s];
        }
        __syncthreads();
    }
    if (tid == 0) out[0] = (float)(r_num[0] / (double)r_cnt[0]);
}

extern "C" void kernel_launch(void* const* d_in, const int* in_sizes, int n_in,
                              void* d_out, int out_size, void* d_ws, size_t ws_size,
                              hipStream_t stream) {
    const float* est       = (const float*)d_in[0];   // (N, K) fp32
    const float* target    = (const float*)d_in[1];   // (N, 2) fp32
    const float* intervals = (const float*)d_in[2];   // (K,)  fp32
    float* out = (float*)d_out;

    float*  mrl  = (float*)d_ws;
    double* pnum = (double*)((char*)d_ws + 32768);
    int*    pcnt = (int*)((char*)d_ws + 40960);

    mrl_kernel<<<N / TPB, TPB, 0, stream>>>(est, intervals, mrl);
    pair_kernel<<<NBLK, TPB, 0, stream>>>(target, mrl, pnum, pcnt);
    final_kernel<<<1, TPB, 0, stream>>>(pnum, pcnt, out);
}